// Round 9
// baseline (1086.978 us; speedup 1.0000x reference)
//
#include <hip/hip_runtime.h>
#include <hip/hip_bf16.h>

#define BATCH 256
#define SEQ   256
#define IND   128
#define HID   1024
#define OUTD  10

#define NCOLG 16           // 16 column groups of 64 cols
#define NROWG 16           // 16 row groups of 16 rows  => grid 256 (proven size)
#define ROWG_ELEMS (HID*16)     // one rowg h-tile: 16384 bf16 = 32 KB
#define CTR_OFF (2*BATCH*HID)   // flags after the two H buffers (proven offset)

typedef __bf16 bf16x8 __attribute__((ext_vector_type(8)));
typedef float  f32x4  __attribute__((ext_vector_type(4)));
typedef unsigned long long u64;

// out-of-band tag bits: bit14 of each 4B half of a u64 (elements 0 and 2).
// |tanh| <= 1 => bf16 exponent <= 127 => bit14 naturally 0.
#define TAGMASK ((1ULL<<14) | (1ULL<<46))

union Pack4 { u64 q; __bf16 h[4]; unsigned short u[4]; };
union Pack8 { u64 q[2]; bf16x8 v; };

__device__ __forceinline__ float fast_tanh(float z) {
    float e = __expf(-2.0f * fabsf(z));
    float t = (1.0f - e) / (1.0f + e);
    return copysignf(t, z);
}

// HYBRID sync: producer side is BYTE-IDENTICAL to the proven R0 kernel
// (store -> __syncthreads vmcnt-drain -> tid0 WG-flag), plus tag bits τ(t) =
// ((t+2)>>1)&1 ORed into bit14 of both 4B halves of every stored u64
// (stripped by all consumers => consumed values bit-exact vs R0).
// Consumer fast path: speculative loads + tag validation (want τ(t-1) =
// ((t+1)>>1)&1 in BOTH halves of all 16 u64s; 4B halves are individually
// atomic; same-slot prior write has τ complement; distance-4 ABA excluded by
// per-location read monotonicity — this lane validated the same slots at
// t-2; memset-0 h buffers => initial garbage can't validate). After 8 failed
// retries: fall back to the EXACT R0 flag-poll + fresh reload. Correctness
// therefore never depends on the tag path being fast or even functional.

__global__ __launch_bounds__(256, 1)
void rnn_persistent(const float* __restrict__ x,
                    const float* __restrict__ Whx,
                    const float* __restrict__ Whh,
                    const float* __restrict__ bh,
                    const float* __restrict__ Why,
                    const float* __restrict__ bo,
                    float* __restrict__ out,
                    __bf16* __restrict__ ws)
{
    const int tid  = threadIdx.x;
    const int lane = tid & 63;
    const int wave = tid >> 6;
    const int bx   = blockIdx.x;
    const int colg = bx & (NCOLG-1);
    const int rowg = bx >> 4;          // 0..15
    const int c0 = colg * 64;
    const int r0 = rowg * 16;
    const int ln15 = lane & 15;
    const int quad = lane >> 4;        // 0..3

    __bf16* hb = ws;
    int* flags  = (int*)(ws + CTR_OFF);
    int* myflag = flags + rowg*16 + colg;
    int* pollp  = flags + rowg*16 + wave*4 + (lane & 3);

    __shared__ float red[4][16][64];   // 16 KB: cross-wave K-reduction

    // ---- one-time: register-resident B fragments (16x16x32 layout:
    // n = lane&15, k = quad*8 + j). Whh HI-ONLY; x-side keeps hi/lo.
    bf16x8 whh_hi[4][8];               // 4 col-tiles x 8 K-chunks of 32
    #pragma unroll
    for (int ct = 0; ct < 4; ++ct) {
        const int nn = c0 + ct*16 + ln15;
        #pragma unroll
        for (int c = 0; c < 8; ++c) {
            const int kb = wave*256 + c*32 + quad*8;
            #pragma unroll
            for (int j = 0; j < 8; ++j)
                whh_hi[ct][c][j] = (__bf16)Whh[(size_t)(kb + j)*HID + nn];
        }
    }
    bf16x8 whx_hi[4], whx_lo[4];
    #pragma unroll
    for (int ct = 0; ct < 4; ++ct) {
        const int nn = c0 + ct*16 + ln15;
        const int kb = wave*32 + quad*8;
        #pragma unroll
        for (int j = 0; j < 8; ++j) {
            float v = Whx[(size_t)(kb + j)*HID + nn];
            __bf16 h = (__bf16)v;
            whx_hi[ct][j] = h;
            whx_lo[ct][j] = (__bf16)(v - (float)h);
        }
    }
    const int srow = tid >> 4;          // 0..15
    const int scol = (tid & 15) * 4;    // 0..60
    const float4 bh4 = *(const float4*)(bh + c0 + scol);
    const size_t xrow_base = (size_t)(r0 + ln15) * (SEQ*IND) + wave*32 + quad*8;
    const int sc = c0 + scol;
    const int soffq = (sc >> 5)*128 + (((sc & 31) >> 3)*16 + srow)*2 + ((sc >> 2) & 1);

    for (int t = 0; t < SEQ; ++t) {
        const int cur = t & 1;
        const int nxt = cur ^ 1;
        f32x4 acc0{}, acc1{}, acc2{}, acc3{};

        // ---- speculative h loads: issued before the x-part so the flight
        // hides under the x MFMAs. Tag-validated (or flag-fallback) below.
        Pack8 pa[8];
        const u64* hq = (const u64*)(hb + (size_t)(cur*NROWG + rowg)*ROWG_ELEMS);
        if (t > 0) {
            #pragma unroll
            for (int c = 0; c < 8; ++c) {
                const int idx = (wave*8 + c)*128 + lane*2;
                pa[c].q[0] = __hip_atomic_load(hq + idx,     __ATOMIC_RELAXED, __HIP_MEMORY_SCOPE_AGENT);
                pa[c].q[1] = __hip_atomic_load(hq + idx + 1, __ATOMIC_RELAXED, __HIP_MEMORY_SCOPE_AGENT);
            }
        }

        // ---- x(t) contribution (h-independent). 3-pass hi/lo.
        {
            const float* xp = x + xrow_base + (size_t)t*IND;
            float4 v0 = ((const float4*)xp)[0];
            float4 v1 = ((const float4*)xp)[1];
            float vv[8] = {v0.x,v0.y,v0.z,v0.w,v1.x,v1.y,v1.z,v1.w};
            bf16x8 ahi, alo;
            #pragma unroll
            for (int j = 0; j < 8; ++j) {
                __bf16 h = (__bf16)vv[j];
                ahi[j] = h;
                alo[j] = (__bf16)(vv[j] - (float)h);
            }
            acc0 = __builtin_amdgcn_mfma_f32_16x16x32_bf16(ahi, whx_hi[0], acc0, 0,0,0);
            acc0 = __builtin_amdgcn_mfma_f32_16x16x32_bf16(alo, whx_hi[0], acc0, 0,0,0);
            acc0 = __builtin_amdgcn_mfma_f32_16x16x32_bf16(ahi, whx_lo[0], acc0, 0,0,0);
            acc1 = __builtin_amdgcn_mfma_f32_16x16x32_bf16(ahi, whx_hi[1], acc1, 0,0,0);
            acc1 = __builtin_amdgcn_mfma_f32_16x16x32_bf16(alo, whx_hi[1], acc1, 0,0,0);
            acc1 = __builtin_amdgcn_mfma_f32_16x16x32_bf16(ahi, whx_lo[1], acc1, 0,0,0);
            acc2 = __builtin_amdgcn_mfma_f32_16x16x32_bf16(ahi, whx_hi[2], acc2, 0,0,0);
            acc2 = __builtin_amdgcn_mfma_f32_16x16x32_bf16(alo, whx_hi[2], acc2, 0,0,0);
            acc2 = __builtin_amdgcn_mfma_f32_16x16x32_bf16(ahi, whx_lo[2], acc2, 0,0,0);
            acc3 = __builtin_amdgcn_mfma_f32_16x16x32_bf16(ahi, whx_hi[3], acc3, 0,0,0);
            acc3 = __builtin_amdgcn_mfma_f32_16x16x32_bf16(alo, whx_hi[3], acc3, 0,0,0);
            acc3 = __builtin_amdgcn_mfma_f32_16x16x32_bf16(ahi, whx_lo[3], acc3, 0,0,0);
        }

        if (t > 0) {
            // ---- fast path: tag validation with bounded retries
            const u64 want = (u64)((((unsigned)t + 1u) >> 1) & 1u);
            bool good = false;
            #pragma unroll 1
            for (int r = 0; r < 8; ++r) {
                unsigned ok = 1u;
                #pragma unroll
                for (int c = 0; c < 8; ++c) {
                    ok &= (unsigned)(((pa[c].q[0] >> 14) & 1ULL) == want);
                    ok &= (unsigned)(((pa[c].q[0] >> 46) & 1ULL) == want);
                    ok &= (unsigned)(((pa[c].q[1] >> 14) & 1ULL) == want);
                    ok &= (unsigned)(((pa[c].q[1] >> 46) & 1ULL) == want);
                }
                if (__all((int)ok)) { good = true; break; }
                #pragma unroll
                for (int c = 0; c < 8; ++c) {
                    const int idx = (wave*8 + c)*128 + lane*2;
                    pa[c].q[0] = __hip_atomic_load(hq + idx,     __ATOMIC_RELAXED, __HIP_MEMORY_SCOPE_AGENT);
                    pa[c].q[1] = __hip_atomic_load(hq + idx + 1, __ATOMIC_RELAXED, __HIP_MEMORY_SCOPE_AGENT);
                }
            }
            if (!good) {
                // ---- fallback: EXACT R0 protocol (flag poll + fresh reload)
                for (;;) {
                    int v = __hip_atomic_load(pollp, __ATOMIC_RELAXED, __HIP_MEMORY_SCOPE_AGENT);
                    if (__all(v >= t)) break;
                }
                asm volatile("" ::: "memory");
                #pragma unroll
                for (int c = 0; c < 8; ++c) {
                    const int idx = (wave*8 + c)*128 + lane*2;
                    pa[c].q[0] = __hip_atomic_load(hq + idx,     __ATOMIC_RELAXED, __HIP_MEMORY_SCOPE_AGENT);
                    pa[c].q[1] = __hip_atomic_load(hq + idx + 1, __ATOMIC_RELAXED, __HIP_MEMORY_SCOPE_AGENT);
                }
            }
            // strip out-of-band tag bits -> values bit-exact vs R0 baseline
            #pragma unroll
            for (int c = 0; c < 8; ++c) {
                pa[c].q[0] &= ~TAGMASK;
                pa[c].q[1] &= ~TAGMASK;
            }
            __builtin_amdgcn_sched_group_barrier(0x008, 32, 0);  // 32 MFMAs
            #pragma unroll
            for (int c = 0; c < 8; ++c) {
                acc0 = __builtin_amdgcn_mfma_f32_16x16x32_bf16(pa[c].v, whh_hi[0][c], acc0, 0,0,0);
                acc1 = __builtin_amdgcn_mfma_f32_16x16x32_bf16(pa[c].v, whh_hi[1][c], acc1, 0,0,0);
                acc2 = __builtin_amdgcn_mfma_f32_16x16x32_bf16(pa[c].v, whh_hi[2][c], acc2, 0,0,0);
                acc3 = __builtin_amdgcn_mfma_f32_16x16x32_bf16(pa[c].v, whh_hi[3][c], acc3, 0,0,0);
            }
        }

        // ---- cross-wave K reduction through LDS (exact R0)
        #pragma unroll
        for (int r = 0; r < 4; ++r) {
            const int row = quad*4 + r;
            red[wave][row][ln15]      = acc0[r];
            red[wave][row][16 + ln15] = acc1[r];
            red[wave][row][32 + ln15] = acc2[r];
            red[wave][row][48 + ln15] = acc3[r];
        }
        __syncthreads();
        {
            const float4 s0 = *(const float4*)&red[0][srow][scol];
            const float4 s1 = *(const float4*)&red[1][srow][scol];
            const float4 s2 = *(const float4*)&red[2][srow][scol];
            const float4 s3 = *(const float4*)&red[3][srow][scol];
            float z0 = s0.x + s1.x + s2.x + s3.x + bh4.x;
            float z1 = s0.y + s1.y + s2.y + s3.y + bh4.y;
            float z2 = s0.z + s1.z + s2.z + s3.z + bh4.z;
            float z3 = s0.w + s1.w + s2.w + s3.w + bh4.w;
            Pack4 pk;
            pk.h[0] = (__bf16)fast_tanh(z0);
            pk.h[1] = (__bf16)fast_tanh(z1);
            pk.h[2] = (__bf16)fast_tanh(z2);
            pk.h[3] = (__bf16)fast_tanh(z3);
            const unsigned ntag = (((unsigned)t + 2u) >> 1) & 1u;  // tau(t)
            pk.u[0] = (unsigned short)(pk.u[0] | (ntag << 14));
            pk.u[2] = (unsigned short)(pk.u[2] | (ntag << 14));
            u64* hnq = (u64*)(hb + (size_t)(nxt*NROWG + rowg)*ROWG_ELEMS) + soffq;
            __hip_atomic_store(hnq, pk.q, __ATOMIC_RELAXED, __HIP_MEMORY_SCOPE_AGENT);
        }
        // ---- EXACT R0 publish: __syncthreads drains vmcnt(0) per wave =>
        // every wave's store reached the coherence point before tid0 flags.
        __syncthreads();
        if (tid == 0) {
            __hip_atomic_store(myflag, t + 1, __ATOMIC_RELAXED, __HIP_MEMORY_SCOPE_AGENT);
        }
    }

    // ---- epilogue: colg==0 WG of each row-group computes o + softmax
    if (colg == 0) {
        int* epip = flags + rowg*16 + (lane & 15);  // all 16 producers
        for (;;) {
            int v = __hip_atomic_load(epip, __ATOMIC_RELAXED, __HIP_MEMORY_SCOPE_AGENT);
            if (__all(v >= SEQ)) break;
        }
        asm volatile("" ::: "memory");
        __syncthreads();
        const u64* hq0 = (const u64*)(hb + (size_t)(0*NROWG + rowg)*ROWG_ELEMS);
        float* obuf = &red[0][0][0];    // reuse LDS, 160 floats
        for (int idx = tid; idx < 16*OUTD; idx += 256) {
            const int row = idx / OUTD;
            const int c   = idx - row*OUTD;
            float s = bo[c];
            #pragma unroll 8
            for (int k4 = 0; k4 < HID/4; ++k4) {
                const int k = k4*4;
                Pack4 p;
                p.q = __hip_atomic_load(hq0 + (k>>5)*128 + (((k&31)>>3)*16 + row)*2 + ((k>>2)&1),
                                        __ATOMIC_RELAXED, __HIP_MEMORY_SCOPE_AGENT);
                p.q &= ~TAGMASK;            // strip tag bits
                const float* wr = Why + (size_t)k*OUTD + c;
                s += (float)p.h[0]*wr[0] + (float)p.h[1]*wr[OUTD]
                   + (float)p.h[2]*wr[2*OUTD] + (float)p.h[3]*wr[3*OUTD];
            }
            obuf[idx] = s;
        }
        __syncthreads();
        if (tid < 16) {
            float m = -1e30f;
            #pragma unroll
            for (int c = 0; c < OUTD; ++c) m = fmaxf(m, obuf[tid*OUTD+c]);
            float e[OUTD]; float ssum = 0.f;
            #pragma unroll
            for (int c = 0; c < OUTD; ++c) { e[c] = __expf(obuf[tid*OUTD+c] - m); ssum += e[c]; }
            const float inv = 1.0f / ssum;
            #pragma unroll
            for (int c = 0; c < OUTD; ++c) out[(size_t)(r0+tid)*OUTD + c] = e[c]*inv;
        }
    }
}

extern "C" void kernel_launch(void* const* d_in, const int* in_sizes, int n_in,
                              void* d_out, int out_size, void* d_ws, size_t ws_size,
                              hipStream_t stream)
{
    const float* x   = (const float*)d_in[0];
    const float* Whx = (const float*)d_in[1];
    const float* Whh = (const float*)d_in[2];
    const float* bh  = (const float*)d_in[3];
    const float* Why = (const float*)d_in[4];
    const float* bo  = (const float*)d_in[5];
    float* out = (float*)d_out;
    __bf16* ws = (__bf16*)d_ws;

    // Zero BOTH h buffers (tag bit14 = 0 => first fast-path reads, expecting
    // tag 1 in both halves, can never validate garbage) plus the 2 KB flag
    // region (contiguous extent).
    hipMemsetAsync(d_ws, 0, (size_t)CTR_OFF*sizeof(__bf16) + 2048, stream);

    void* args[] = { &x, &Whx, &Whh, &bh, &Why, &bo, &out, &ws };
    hipLaunchCooperativeKernel((const void*)rnn_persistent,
                               dim3(NROWG*NCOLG), dim3(256), args, 0, stream);
}